// Round 4
// baseline (632.992 us; speedup 1.0000x reference)
//
#include <hip/hip_runtime.h>
#include <math.h>

#define NB 32
#define NT 512
#define NC 4233
#define NU 64
#define LABT 129            // 2*NU+1
#define PADV (-3.4028234663852886e38f)   // float32 min (matches jnp.finfo(f32).min)

// emit layout: [B][T][64 float2]; pair k at lane l = {cell l, cell 64+l}
// cell 128 (always blank) shares cell 0's column -> broadcast lane 0's e.x

__device__ __forceinline__ int extcol(int c, const int* label, int b, int blank) {
    if ((c & 1) == 0) return blank;            // even cell = blank
    int raw = label[((c - 1) >> 1) * NB + b];
    int e = (raw == blank) ? -1 : raw;
    int idx = e % NC;                          // python floor-mod: -1 -> NC-1
    if (idx < 0) idx += NC;
    return idx;
}

__device__ __forceinline__ int condcell(int c, const int* label, int b, int blank) {
    if ((c & 1) == 0) return 1;                // blank cells: cond true
    int u = (c - 1) >> 1;
    int raw = label[u * NB + b];
    int e = (raw == blank) ? -1 : raw;
    int s2;
    if (u == 0) s2 = -1;
    else {
        int raw2 = label[(u - 1) * NB + b];
        s2 = (raw2 == blank) ? -1 : raw2;
    }
    return (e == blank) || (e == s2);
}

// ---------------------------------------------------------------------------
// Kernel 0: parallel emit gather  [B][T][128] interleaved pairs
// ---------------------------------------------------------------------------
__global__ void ctc_gather_kernel(const float* __restrict__ logit,  // [B][T][C]
                                  const int*   __restrict__ label,  // [U][B]
                                  const int*   __restrict__ blank_ptr,
                                  float* __restrict__ emit)         // [B][T][128]
{
    int tid = blockIdx.x * blockDim.x + threadIdx.x;   // exact grid: B*T*128
    int blank = blank_ptr[0];
    int k = tid & 127;
    int bt = tid >> 7;                 // b*NT + t
    int b  = bt >> 9;                  // / NT
    int c  = (k & 1) ? 64 + (k >> 1) : (k >> 1);   // cell index 0..127
    int col = extcol(c, label, b, blank);
    emit[tid] = logit[(size_t)bt * NC + col];
}

// ---------------------------------------------------------------------------
// Kernel 1: barrier-free DP scan, one wave per batch.
// ---------------------------------------------------------------------------
__global__ __launch_bounds__(64)
void ctc_scan_kernel(const float* __restrict__ emitb,  // [B][T][128]
                     const int*   __restrict__ label,  // [U][B]
                     const int*   __restrict__ blank_ptr,
                     int*   __restrict__ wout,         // [B][T]
                     float* __restrict__ loss_out)     // [B]
{
    __shared__ unsigned long long bpm[NT][4];   // t-indexed ballot masks (16 KB)
    __shared__ unsigned char     bp2s[NT];      // cell-128 delta
    __shared__ float             dpfin[132];
    __shared__ int               wl[NT];

    const int b = blockIdx.x;
    const int l = threadIdx.x;          // lane 0..63
    const int blank = blank_ptr[0];

    // yl via wave ballot (U == 64 == wave)
    int rawl = label[l * NB + b];
    unsigned long long ylm = __ballot(rawl != blank);
    const int Y = 2 * (int)__popcll(ylm) + 1;

    const int cnd0 = condcell(l,      label, b, blank);
    const int cnd1 = condcell(64 + l, label, b, blank);

    const int lm1 = (l + 63) & 63;      // rotate-by-1 source lane
    const int lm2 = (l + 62) & 63;

    const float2* emrow = (const float2*)emitb + (size_t)b * NT * 64 + l;

    // t = 0 init
    float2 e00 = emrow[0];
    float dp0 = (l <= 1) ? e00.x : PADV;   // cells 0..63
    float dp1 = PADV;                      // cells 64..127
    float dp2 = PADV;                      // cell 128 (lane 63 only meaningful)

    // prefetch ring depth 8 (t = 1..8)
    float2 r0 = emrow[(size_t)1 * 64];
    float2 r1 = emrow[(size_t)2 * 64];
    float2 r2 = emrow[(size_t)3 * 64];
    float2 r3 = emrow[(size_t)4 * 64];
    float2 r4 = emrow[(size_t)5 * 64];
    float2 r5 = emrow[(size_t)6 * 64];
    float2 r6 = emrow[(size_t)7 * 64];
    float2 r7 = emrow[(size_t)8 * 64];

#define STEP(tcur, rr, tload)                                                   \
    do {                                                                         \
        float a0 = dp0, a1 = dp1, a2 = dp2;                                      \
        float q1_0 = __shfl(a0, lm1);     /* dp0[l-1 mod 64] */                  \
        float q2_0 = __shfl(a0, lm2);                                            \
        float q1_1 = __shfl(a1, lm1);                                            \
        float q2_1 = __shfl(a1, lm2);                                            \
        float s0m1 = (l >= 1) ? q1_0 : PADV;                                     \
        float s0m2 = (l >= 2) ? q2_0 : PADV;                                     \
        float s1m1 = (l == 0) ? q1_0 : q1_1;  /* lane0: dp0[63] */               \
        float s1m2 = (l <= 1) ? q2_0 : q2_1;  /* lane0: dp0[62], lane1: dp0[63]*/\
        float c0 = cnd0 ? PADV : s0m2;                                           \
        float c1 = cnd1 ? PADV : s1m2;                                           \
        float m0 = fmaxf(fmaxf(a0, s0m1), c0);                                   \
        float z0 = m0 + logf(expf(a0 - m0) + expf(s0m1 - m0) + expf(c0 - m0));   \
        int   d0 = (a0 >= s0m1 && a0 >= c0) ? 0 : ((s0m1 >= c0) ? 1 : 2);        \
        float m1v = fmaxf(fmaxf(a1, s1m1), c1);                                  \
        float z1 = m1v + logf(expf(a1 - m1v) + expf(s1m1 - m1v) + expf(c1 - m1v));\
        int   d1 = (a1 >= s1m1 && a1 >= c1) ? 0 : ((s1m1 >= c1) ? 1 : 2);        \
        float m2 = fmaxf(a2, a1);             /* cell128: cond always true */    \
        float z2 = m2 + logf(expf(a2 - m2) + expf(a1 - m2));                     \
        int   d2 = (a2 >= a1) ? 0 : 1;                                           \
        float e2 = __int_as_float(__builtin_amdgcn_readfirstlane(                \
                       __float_as_int(rr.x)));  /* blank emit = cell0 emit */    \
        dp0 = rr.x + z0;                                                         \
        dp1 = rr.y + z1;                                                         \
        dp2 = e2   + z2;                                                         \
        unsigned long long b00 = __ballot(d0 & 1);                               \
        unsigned long long b01 = __ballot(d0 >> 1);                              \
        unsigned long long b10 = __ballot(d1 & 1);                               \
        unsigned long long b11 = __ballot(d1 >> 1);                              \
        if (l == 0) {                                                            \
            bpm[tcur][0] = b00; bpm[tcur][1] = b01;                              \
            bpm[tcur][2] = b10; bpm[tcur][3] = b11;                              \
        }                                                                        \
        if (l == 63) bp2s[tcur] = (unsigned char)d2;                             \
        if ((tload) <= NT - 1) rr = emrow[(size_t)(tload) * 64];                 \
    } while (0)

    int t = 1;
    for (; t + 7 <= NT - 1; t += 8) {
        STEP(t,     r0, t + 8);
        STEP(t + 1, r1, t + 9);
        STEP(t + 2, r2, t + 10);
        STEP(t + 3, r3, t + 11);
        STEP(t + 4, r4, t + 12);
        STEP(t + 5, r5, t + 13);
        STEP(t + 6, r6, t + 14);
        STEP(t + 7, r7, t + 15);
    }
    // tail: t = 505..511 (7 steps), ring phase (t-1)&7 continues at r0
    STEP(t,     r0, NT); t++;
    STEP(t,     r1, NT); t++;
    STEP(t,     r2, NT); t++;
    STEP(t,     r3, NT); t++;
    STEP(t,     r4, NT); t++;
    STEP(t,     r5, NT); t++;
    STEP(t,     r6, NT);
#undef STEP

    // final dp row -> LDS
    dpfin[l] = dp0;
    dpfin[64 + l] = dp1;
    if (l == 63) dpfin[128] = dp2;
    __syncthreads();

    if (l == 0) {
        float d1v = dpfin[Y - 1];
        float d2v = dpfin[Y - 2];
        float mm = fmaxf(d1v, d2v);
        float la = mm + logf(expf(d1v - mm) + expf(d2v - mm));
        loss_out[b] = -la * 2.0f / (float)(Y - 1);

        int w = (d1v > d2v) ? (Y - 1) : (Y - 2);
#pragma unroll 4
        for (int tt = NT - 1; tt >= 1; --tt) {
            wl[tt] = w;
            // unconditional loads (t-indexed, w-independent) -> pipelinable
            unsigned long long w0lo = bpm[tt][0], w1lo = bpm[tt][1];
            unsigned long long w0hi = bpm[tt][2], w1hi = bpm[tt][3];
            int dd2 = (int)bp2s[tt];
            unsigned long long m0 = (w < 64) ? w0lo : w0hi;
            unsigned long long m1 = (w < 64) ? w1lo : w1hi;
            int sh = w & 63;
            int dd = (int)((m0 >> sh) & 1ULL) + 2 * (int)((m1 >> sh) & 1ULL);
            if (w == 128) dd = dd2;
            w -= dd;
        }
        wl[0] = w;
    }
    __syncthreads();
    for (int tt = l; tt < NT; tt += 64) wout[b * NT + tt] = wl[tt];
}

// ---------------------------------------------------------------------------
// Kernel 2: one-hot align write (float32), full coverage of align region
// ---------------------------------------------------------------------------
__global__ void ctc_align_kernel(const int* __restrict__ w,   // [B*T]
                                 float* __restrict__ out)     // [B][T][LABT]
{
    int tid = blockIdx.x * blockDim.x + threadIdx.x;
    if (tid >= NB * NT * LABT) return;
    int j  = tid % LABT;
    int bt = tid / LABT;
    out[tid] = (j == w[bt]) ? 1.0f : 0.0f;
}

// ---------------------------------------------------------------------------
extern "C" void kernel_launch(void* const* d_in, const int* in_sizes, int n_in,
                              void* d_out, int out_size, void* d_ws, size_t ws_size,
                              hipStream_t stream)
{
    const float* logit = (const float*)d_in[0];
    const int*   label = (const int*)d_in[1];
    const int*   blank = (const int*)d_in[2];

    float* out = (float*)d_out;   // [B*T*LABT] align (0/1 float) then [B] loss
    int*   ws  = (int*)d_ws;

    int*   wout = ws;                                  // 32*512 ints = 64 KB
    size_t emit_elems = (size_t)NB * NT * 128;
    bool   use_ws = ws_size >= (size_t)NB * NT * 4 + emit_elems * 4 + 256;
    // fallback: stage emit in the align region of d_out (overwritten later by
    // ctc_align_kernel; stream order guarantees scan reads it first)
    float* emit = use_ws ? (float*)(ws + NB * NT) : out;

    ctc_gather_kernel<<<(int)(emit_elems / 256), 256, 0, stream>>>(
        logit, label, blank, emit);
    ctc_scan_kernel<<<NB, 64, 0, stream>>>(emit, label, blank, wout,
                                           out + (size_t)NB * NT * LABT);
    int total = NB * NT * LABT;
    ctc_align_kernel<<<(total + 255) / 256, 256, 0, stream>>>(wout, out);
}

// Round 5
// 546.962 us; speedup vs baseline: 1.1573x; 1.1573x over previous
//
#include <hip/hip_runtime.h>
#include <math.h>

#define NB 32
#define NT 512
#define NC 4233
#define NU 64
#define LABT 129            // 2*NU+1
#define PADV (-3.4028234663852886e38f)   // float32 min (matches jnp.finfo(f32).min)

// emit layout: [B][T][64 float2]; pair k at lane l = {cell l, cell 64+l}
// cell 128 (always blank) shares cell 0's column -> broadcast lane 0's e.x

__device__ __forceinline__ int extcol(int c, const int* label, int b, int blank) {
    if ((c & 1) == 0) return blank;            // even cell = blank
    int raw = label[((c - 1) >> 1) * NB + b];
    int e = (raw == blank) ? -1 : raw;
    int idx = e % NC;                          // python floor-mod: -1 -> NC-1
    if (idx < 0) idx += NC;
    return idx;
}

__device__ __forceinline__ int condcell(int c, const int* label, int b, int blank) {
    if ((c & 1) == 0) return 1;                // blank cells: cond true
    int u = (c - 1) >> 1;
    int raw = label[u * NB + b];
    int e = (raw == blank) ? -1 : raw;
    int s2;
    if (u == 0) s2 = -1;
    else {
        int raw2 = label[(u - 1) * NB + b];
        s2 = (raw2 == blank) ? -1 : raw2;
    }
    return (e == blank) || (e == s2);
}

// ---------------------------------------------------------------------------
// Kernel 0: parallel emit gather  [B][T][128] interleaved pairs
// ---------------------------------------------------------------------------
__global__ void ctc_gather_kernel(const float* __restrict__ logit,  // [B][T][C]
                                  const int*   __restrict__ label,  // [U][B]
                                  const int*   __restrict__ blank_ptr,
                                  float* __restrict__ emit)         // [B][T][128]
{
    int tid = blockIdx.x * blockDim.x + threadIdx.x;   // exact grid: B*T*128
    int blank = blank_ptr[0];
    int k = tid & 127;
    int bt = tid >> 7;                 // b*NT + t
    int b  = bt >> 9;                  // / NT
    int c  = (k & 1) ? 64 + (k >> 1) : (k >> 1);   // cell index 0..127
    int col = extcol(c, label, b, blank);
    emit[tid] = logit[(size_t)bt * NC + col];
}

// ---------------------------------------------------------------------------
// Kernel 1: barrier-free DP scan, one wave per batch.  Fast-math exp/log.
// ---------------------------------------------------------------------------
__global__ __launch_bounds__(64)
void ctc_scan_kernel(const float* __restrict__ emitb,  // [B][T][128]
                     const int*   __restrict__ label,  // [U][B]
                     const int*   __restrict__ blank_ptr,
                     int*   __restrict__ wout,         // [B][T]
                     float* __restrict__ loss_out)     // [B]
{
    __shared__ unsigned long long bpm[NT][4];   // t-indexed ballot masks (16 KB)
    __shared__ unsigned char     bp2s[NT];      // cell-128 delta
    __shared__ float             dpfin[132];
    __shared__ int               wl[NT];

    const int b = blockIdx.x;
    const int l = threadIdx.x;          // lane 0..63
    const int blank = blank_ptr[0];

    // yl via wave ballot (U == 64 == wave)
    int rawl = label[l * NB + b];
    unsigned long long ylm = __ballot(rawl != blank);
    const int Y = 2 * (int)__popcll(ylm) + 1;

    const int cnd0 = condcell(l,      label, b, blank);
    const int cnd1 = condcell(64 + l, label, b, blank);

    const int lm1 = (l + 63) & 63;      // rotate-by-1 source lane
    const int lm2 = (l + 62) & 63;

    const float2* emrow = (const float2*)emitb + (size_t)b * NT * 64 + l;

    // t = 0 init
    float2 e00 = emrow[0];
    float dp0 = (l <= 1) ? e00.x : PADV;   // cells 0..63
    float dp1 = PADV;                      // cells 64..127
    float dp2 = PADV;                      // cell 128 (lane 63 only meaningful)

    // prefetch ring depth 8 (t = 1..8)
    float2 r0 = emrow[(size_t)1 * 64];
    float2 r1 = emrow[(size_t)2 * 64];
    float2 r2 = emrow[(size_t)3 * 64];
    float2 r3 = emrow[(size_t)4 * 64];
    float2 r4 = emrow[(size_t)5 * 64];
    float2 r5 = emrow[(size_t)6 * 64];
    float2 r6 = emrow[(size_t)7 * 64];
    float2 r7 = emrow[(size_t)8 * 64];

#define STEP(tcur, rr, tload)                                                   \
    do {                                                                         \
        float a0 = dp0, a1 = dp1, a2 = dp2;                                      \
        float q1_0 = __shfl(a0, lm1);     /* dp0[l-1 mod 64] */                  \
        float q2_0 = __shfl(a0, lm2);                                            \
        float q1_1 = __shfl(a1, lm1);                                            \
        float q2_1 = __shfl(a1, lm2);                                            \
        float s0m1 = (l >= 1) ? q1_0 : PADV;                                     \
        float s0m2 = (l >= 2) ? q2_0 : PADV;                                     \
        float s1m1 = (l == 0) ? q1_0 : q1_1;  /* lane0: dp0[63] */               \
        float s1m2 = (l <= 1) ? q2_0 : q2_1;  /* lane0: dp0[62], lane1: dp0[63]*/\
        float c0 = cnd0 ? PADV : s0m2;                                           \
        float c1 = cnd1 ? PADV : s1m2;                                           \
        float m0 = fmaxf(fmaxf(a0, s0m1), c0);                                   \
        float z0 = m0 + __logf(__expf(a0 - m0) + __expf(s0m1 - m0) +             \
                               __expf(c0 - m0));                                 \
        int   d0 = (a0 >= s0m1 && a0 >= c0) ? 0 : ((s0m1 >= c0) ? 1 : 2);        \
        float m1v = fmaxf(fmaxf(a1, s1m1), c1);                                  \
        float z1 = m1v + __logf(__expf(a1 - m1v) + __expf(s1m1 - m1v) +          \
                                __expf(c1 - m1v));                               \
        int   d1 = (a1 >= s1m1 && a1 >= c1) ? 0 : ((s1m1 >= c1) ? 1 : 2);        \
        float m2 = fmaxf(a2, a1);             /* cell128: cond always true */    \
        float z2 = m2 + __logf(__expf(a2 - m2) + __expf(a1 - m2));               \
        int   d2 = (a2 >= a1) ? 0 : 1;                                           \
        float e2 = __int_as_float(__builtin_amdgcn_readfirstlane(                \
                       __float_as_int(rr.x)));  /* blank emit = cell0 emit */    \
        dp0 = rr.x + z0;                                                         \
        dp1 = rr.y + z1;                                                         \
        dp2 = e2   + z2;                                                         \
        unsigned long long b00 = __ballot(d0 & 1);                               \
        unsigned long long b01 = __ballot(d0 >> 1);                              \
        unsigned long long b10 = __ballot(d1 & 1);                               \
        unsigned long long b11 = __ballot(d1 >> 1);                              \
        if (l == 0) {                                                            \
            bpm[tcur][0] = b00; bpm[tcur][1] = b01;                              \
            bpm[tcur][2] = b10; bpm[tcur][3] = b11;                              \
        }                                                                        \
        if (l == 63) bp2s[tcur] = (unsigned char)d2;                             \
        if ((tload) <= NT - 1) rr = emrow[(size_t)(tload) * 64];                 \
    } while (0)

    int t = 1;
    for (; t + 7 <= NT - 1; t += 8) {
        STEP(t,     r0, t + 8);
        STEP(t + 1, r1, t + 9);
        STEP(t + 2, r2, t + 10);
        STEP(t + 3, r3, t + 11);
        STEP(t + 4, r4, t + 12);
        STEP(t + 5, r5, t + 13);
        STEP(t + 6, r6, t + 14);
        STEP(t + 7, r7, t + 15);
    }
    // tail: t = 505..511 (7 steps), ring phase (t-1)&7 continues at r0
    STEP(t,     r0, NT); t++;
    STEP(t,     r1, NT); t++;
    STEP(t,     r2, NT); t++;
    STEP(t,     r3, NT); t++;
    STEP(t,     r4, NT); t++;
    STEP(t,     r5, NT); t++;
    STEP(t,     r6, NT);
#undef STEP

    // final dp row -> LDS
    dpfin[l] = dp0;
    dpfin[64 + l] = dp1;
    if (l == 63) dpfin[128] = dp2;
    __syncthreads();

    if (l == 0) {
        float d1v = dpfin[Y - 1];
        float d2v = dpfin[Y - 2];
        float mm = fmaxf(d1v, d2v);
        float la = mm + __logf(__expf(d1v - mm) + __expf(d2v - mm));
        loss_out[b] = -la * 2.0f / (float)(Y - 1);

        int w = (d1v > d2v) ? (Y - 1) : (Y - 2);
#pragma unroll 4
        for (int tt = NT - 1; tt >= 1; --tt) {
            wl[tt] = w;
            // unconditional loads (t-indexed, w-independent) -> pipelinable
            unsigned long long w0lo = bpm[tt][0], w1lo = bpm[tt][1];
            unsigned long long w0hi = bpm[tt][2], w1hi = bpm[tt][3];
            int dd2 = (int)bp2s[tt];
            unsigned long long m0 = (w < 64) ? w0lo : w0hi;
            unsigned long long m1 = (w < 64) ? w1lo : w1hi;
            int sh = w & 63;
            int dd = (int)((m0 >> sh) & 1ULL) + 2 * (int)((m1 >> sh) & 1ULL);
            if (w == 128) dd = dd2;
            w -= dd;
        }
        wl[0] = w;
    }
    __syncthreads();
    for (int tt = l; tt < NT; tt += 64) wout[b * NT + tt] = wl[tt];
}

// ---------------------------------------------------------------------------
// Kernel 2: one-hot align write (float32), full coverage of align region
// ---------------------------------------------------------------------------
__global__ void ctc_align_kernel(const int* __restrict__ w,   // [B*T]
                                 float* __restrict__ out)     // [B][T][LABT]
{
    int tid = blockIdx.x * blockDim.x + threadIdx.x;
    if (tid >= NB * NT * LABT) return;
    int j  = tid % LABT;
    int bt = tid / LABT;
    out[tid] = (j == w[bt]) ? 1.0f : 0.0f;
}

// ---------------------------------------------------------------------------
extern "C" void kernel_launch(void* const* d_in, const int* in_sizes, int n_in,
                              void* d_out, int out_size, void* d_ws, size_t ws_size,
                              hipStream_t stream)
{
    const float* logit = (const float*)d_in[0];
    const int*   label = (const int*)d_in[1];
    const int*   blank = (const int*)d_in[2];

    float* out = (float*)d_out;   // [B*T*LABT] align (0/1 float) then [B] loss
    int*   ws  = (int*)d_ws;

    int*   wout = ws;                                  // 32*512 ints = 64 KB
    size_t emit_elems = (size_t)NB * NT * 128;
    bool   use_ws = ws_size >= (size_t)NB * NT * 4 + emit_elems * 4 + 256;
    // fallback: stage emit in the align region of d_out (overwritten later by
    // ctc_align_kernel; stream order guarantees scan reads it first)
    float* emit = use_ws ? (float*)(ws + NB * NT) : out;

    ctc_gather_kernel<<<(int)(emit_elems / 256), 256, 0, stream>>>(
        logit, label, blank, emit);
    ctc_scan_kernel<<<NB, 64, 0, stream>>>(emit, label, blank, wout,
                                           out + (size_t)NB * NT * LABT);
    int total = NB * NT * LABT;
    ctc_align_kernel<<<(total + 255) / 256, 256, 0, stream>>>(wout, out);
}

// Round 6
// 533.089 us; speedup vs baseline: 1.1874x; 1.0260x over previous
//
#include <hip/hip_runtime.h>
#include <math.h>

#define NB 32
#define NT 512
#define NC 4233
#define NU 64
#define LABT 129            // 2*NU+1
#define PADV (-3.4028234663852886e38f)   // float32 min (matches jnp.finfo(f32).min)

// Cell layout: lane l holds cells 2l (even=blank) and 2l+1 (odd=label l).
// Cell 128 (blank) is carried uniformly in dp2 on all lanes.
// emit: eo[b][t][l] = logit[b,t,col(label l)]  (odd cells)
//       eb[b][t]    = logit[b,t,blank]         (all even cells + cell 128)

__device__ __forceinline__ float wave_shr1(float x, float fill) {
    // lane l gets lane l-1's x; lane 0 gets `fill` (bound_ctrl=false -> old)
    int r = __builtin_amdgcn_update_dpp(__float_as_int(fill), __float_as_int(x),
                                        0x138, 0xF, 0xF, false);
    return __int_as_float(r);
}

__device__ __forceinline__ int oddcol(int u, const int* label, int b, int blank) {
    int raw = label[u * NB + b];
    int e = (raw == blank) ? -1 : raw;
    int idx = e % NC;                          // python floor-mod: -1 -> NC-1
    if (idx < 0) idx += NC;
    return idx;
}

__device__ __forceinline__ int oddcond(int u, const int* label, int b, int blank) {
    int raw = label[u * NB + b];
    int e = (raw == blank) ? -1 : raw;
    int s2;
    if (u == 0) s2 = -1;
    else {
        int raw2 = label[(u - 1) * NB + b];
        s2 = (raw2 == blank) ? -1 : raw2;
    }
    return (e == blank) || (e == s2);
}

// ---------------------------------------------------------------------------
// Kernel 0: parallel emit gather
// ---------------------------------------------------------------------------
__global__ void ctc_gather_kernel(const float* __restrict__ logit,  // [B][T][C]
                                  const int*   __restrict__ label,  // [U][B]
                                  const int*   __restrict__ blank_ptr,
                                  float* __restrict__ eo,           // [B][T][64]
                                  float* __restrict__ eb)           // [B][T]
{
    int tid = blockIdx.x * blockDim.x + threadIdx.x;   // exact grid: B*T*64
    int blank = blank_ptr[0];
    int k  = tid & 63;
    int bt = tid >> 6;                 // b*NT + t
    int b  = bt >> 9;                  // / NT
    int col = oddcol(k, label, b, blank);
    eo[tid] = logit[(size_t)bt * NC + col];
    if (k == 0) eb[bt] = logit[(size_t)bt * NC + blank];
}

// ---------------------------------------------------------------------------
// Kernel 1: DPP-based DP scan, one wave per batch, zero ds_bpermute.
// ---------------------------------------------------------------------------
__global__ __launch_bounds__(64)
void ctc_scan_kernel(const float* __restrict__ eo,     // [B][T][64]
                     const float* __restrict__ ebg,    // [B][T]
                     const int*   __restrict__ label,  // [U][B]
                     const int*   __restrict__ blank_ptr,
                     int*   __restrict__ wout,         // [B][T]
                     float* __restrict__ loss_out)     // [B]
{
    __shared__ unsigned long long bpm[NT][3];   // ballots: even, odd&1, odd>>1
    __shared__ unsigned char     bp2s[NT];      // cell-128 delta (uniform)
    __shared__ float             dpfin[132];
    __shared__ int               wl[NT];

    const int b = blockIdx.x;
    const int l = threadIdx.x;          // lane 0..63
    const int blank = blank_ptr[0];

    int rawl = label[l * NB + b];
    unsigned long long ylm = __ballot(rawl != blank);
    const int Y = 2 * (int)__popcll(ylm) + 1;

    const int cnd1 = oddcond(l, label, b, blank);   // cond of odd cell 2l+1

    const float* eor = eo  + ((size_t)b * NT) * 64 + l;
    const float* ebr = ebg + (size_t)b * NT;

    // t = 0 init: dp[0]=eb_0, dp[1]=eo_0[0], rest PAD
    float eb0 = ebr[0];
    float eo0 = eor[0];
    float dp0 = (l == 0) ? eb0 : PADV;   // even cells 2l
    float dp1 = (l == 0) ? eo0 : PADV;   // odd cells 2l+1
    float dp2 = PADV;                    // cell 128 (uniform)

    // prefetch ring depth 8 (t = 1..8)
    float r0 = eor[(size_t)1 * 64], s0 = ebr[1];
    float r1 = eor[(size_t)2 * 64], s1r = ebr[2];
    float r2 = eor[(size_t)3 * 64], s2r = ebr[3];
    float r3 = eor[(size_t)4 * 64], s3r = ebr[4];
    float r4 = eor[(size_t)5 * 64], s4r = ebr[5];
    float r5 = eor[(size_t)6 * 64], s5r = ebr[6];
    float r6 = eor[(size_t)7 * 64], s6r = ebr[7];
    float r7 = eor[(size_t)8 * 64], s7r = ebr[8];

#define STEP(tcur, rr, sb, tload)                                                \
    do {                                                                         \
        float a0 = dp0, a1 = dp1, a2 = dp2;                                      \
        float sp = wave_shr1(a1, PADV);    /* dp[2l-1]: prev lane's odd */       \
        /* even cell 2l (blank, cond): 2-way lse(a0, sp) */                      \
        float m0 = fmaxf(a0, sp);                                                \
        float z0 = m0 + __logf(__expf(a0 - m0) + __expf(sp - m0));               \
        unsigned long long bb0 = __ballot(a0 < sp);      /* delta0: 0/1 */       \
        /* odd cell 2l+1: (a1, a0_own, sp masked by cond) */                     \
        float c1 = cnd1 ? PADV : sp;                                             \
        float m1 = fmaxf(fmaxf(a1, a0), c1);                                     \
        float z1 = m1 + __logf(__expf(a1 - m1) + __expf(a0 - m1) +               \
                               __expf(c1 - m1));                                 \
        int d1 = (a1 >= a0 && a1 >= c1) ? 0 : ((a0 >= c1) ? 1 : 2);              \
        unsigned long long bb1 = __ballot(d1 & 1);                               \
        unsigned long long bb2 = __ballot(d1 >> 1);                              \
        /* cell 128 (blank): 2-way lse(a2, dp[127]=lane63 odd), uniform */       \
        float s127 = __int_as_float(                                             \
            __builtin_amdgcn_readlane(__float_as_int(a1), 63));                  \
        float m2 = fmaxf(a2, s127);                                              \
        float z2 = m2 + __logf(__expf(a2 - m2) + __expf(s127 - m2));             \
        int d2u = (a2 >= s127) ? 0 : 1;                                          \
        dp0 = sb + z0;                                                           \
        dp1 = rr + z1;                                                           \
        dp2 = sb + z2;                                                           \
        if (l == 0) {                                                            \
            bpm[tcur][0] = bb0; bpm[tcur][1] = bb1; bpm[tcur][2] = bb2;          \
            bp2s[tcur] = (unsigned char)d2u;                                     \
        }                                                                        \
        if ((tload) <= NT - 1) { rr = eor[(size_t)(tload) * 64];                 \
                                 sb = ebr[tload]; }                              \
    } while (0)

    int t = 1;
    for (; t + 7 <= NT - 1; t += 8) {
        STEP(t,     r0, s0,  t + 8);
        STEP(t + 1, r1, s1r, t + 9);
        STEP(t + 2, r2, s2r, t + 10);
        STEP(t + 3, r3, s3r, t + 11);
        STEP(t + 4, r4, s4r, t + 12);
        STEP(t + 5, r5, s5r, t + 13);
        STEP(t + 6, r6, s6r, t + 14);
        STEP(t + 7, r7, s7r, t + 15);
    }
    // tail: t = 505..511 (7 steps)
    STEP(t,     r0, s0,  NT); t++;
    STEP(t,     r1, s1r, NT); t++;
    STEP(t,     r2, s2r, NT); t++;
    STEP(t,     r3, s3r, NT); t++;
    STEP(t,     r4, s4r, NT); t++;
    STEP(t,     r5, s5r, NT); t++;
    STEP(t,     r6, s6r, NT);
#undef STEP

    // final dp row -> LDS
    dpfin[2 * l]     = dp0;
    dpfin[2 * l + 1] = dp1;
    if (l == 0) dpfin[128] = dp2;
    __syncthreads();

    if (l == 0) {
        float d1v = dpfin[Y - 1];
        float d2v = dpfin[Y - 2];
        float mm = fmaxf(d1v, d2v);
        float la = mm + __logf(__expf(d1v - mm) + __expf(d2v - mm));
        loss_out[b] = -la * 2.0f / (float)(Y - 1);

        int w = (d1v > d2v) ? (Y - 1) : (Y - 2);
#pragma unroll 4
        for (int tt = NT - 1; tt >= 1; --tt) {
            wl[tt] = w;
            unsigned long long B0 = bpm[tt][0];
            unsigned long long B1 = bpm[tt][1];
            unsigned long long B2 = bpm[tt][2];
            int d2v2 = (int)bp2s[tt];
            int li = w >> 1;
            int dd;
            if (w == 128)     dd = d2v2;
            else if (w & 1)   dd = (int)((B1 >> li) & 1ULL) + 2 * (int)((B2 >> li) & 1ULL);
            else              dd = (int)((B0 >> li) & 1ULL);
            w -= dd;
        }
        wl[0] = w;
    }
    __syncthreads();
    for (int tt = l; tt < NT; tt += 64) wout[b * NT + tt] = wl[tt];
}

// ---------------------------------------------------------------------------
// Kernel 2: one-hot align write (float32), full coverage of align region
// ---------------------------------------------------------------------------
__global__ void ctc_align_kernel(const int* __restrict__ w,   // [B*T]
                                 float* __restrict__ out)     // [B][T][LABT]
{
    int tid = blockIdx.x * blockDim.x + threadIdx.x;
    if (tid >= NB * NT * LABT) return;
    int j  = tid % LABT;
    int bt = tid / LABT;
    out[tid] = (j == w[bt]) ? 1.0f : 0.0f;
}

// ---------------------------------------------------------------------------
extern "C" void kernel_launch(void* const* d_in, const int* in_sizes, int n_in,
                              void* d_out, int out_size, void* d_ws, size_t ws_size,
                              hipStream_t stream)
{
    const float* logit = (const float*)d_in[0];
    const int*   label = (const int*)d_in[1];
    const int*   blank = (const int*)d_in[2];

    float* out = (float*)d_out;   // [B*T*LABT] align (0/1 float) then [B] loss
    int*   ws  = (int*)d_ws;

    int*   wout = ws;                                   // 32*512 ints
    size_t need = (size_t)NB * NT * 4                   // wout
                + (size_t)NB * NT * 4                   // eb
                + (size_t)NB * NT * 64 * 4 + 256;       // eo
    bool   use_ws = ws_size >= need;
    float* ebp, *eop;
    if (use_ws) {
        ebp = (float*)(ws + NB * NT);
        eop = ebp + NB * NT;
    } else {
        // stage in align region of d_out (scan reads before align kernel writes)
        ebp = out;
        eop = out + NB * NT;
    }

    ctc_gather_kernel<<<NB * NT * 64 / 256, 256, 0, stream>>>(
        logit, label, blank, eop, ebp);
    ctc_scan_kernel<<<NB, 64, 0, stream>>>(eop, ebp, label, blank, wout,
                                           out + (size_t)NB * NT * LABT);
    int total = NB * NT * LABT;
    ctc_align_kernel<<<(total + 255) / 256, 256, 0, stream>>>(wout, out);
}